// Round 4
// baseline (508.952 us; speedup 1.0000x reference)
//
#include <hip/hip_runtime.h>
#include <hip/hip_bf16.h>

#define INV_SQRT2 0.7071067811865475f

typedef __attribute__((ext_vector_type(8))) short short8;
typedef __attribute__((ext_vector_type(4))) float f32x4;

static __device__ __forceinline__ unsigned short f2bf(float f) {
  __hip_bfloat16 h = __float2bfloat16(f);
  return *(unsigned short*)&h;
}
static __device__ __forceinline__ float bf2f(unsigned short u) {
  unsigned int bits = ((unsigned int)u) << 16;
  return __uint_as_float(bits);
}

// ---------- prep: bf16 weight copies (+ legacy f32 k-major WT) ----------
__global__ __launch_bounds__(256) void prep_kernel(
    const float* __restrict__ W_edge, const float* __restrict__ W_nn,
    const float* __restrict__ W_res, float* __restrict__ WT,
    unsigned short* __restrict__ Web, unsigned short* __restrict__ Wnb,
    unsigned short* __restrict__ Wrb) {
  int idx = blockIdx.x * 256 + threadIdx.x;
  if (idx < 8192) Web[idx] = f2bf(W_edge[idx]);
  if (idx < 16384) {
    Wnb[idx] = f2bf(W_nn[idx]);
    Wrb[idx] = f2bf(W_res[idx]);
    int o = idx >> 7, k = idx & 127;
    WT[k * 128 + o] = W_nn[idx];
    WT[16384 + k * 128 + o] = W_res[idx];
  }
}

// ---------- CSR build ----------
__global__ __launch_bounds__(256) void hist_kernel(const int* __restrict__ ei,
                                                   int* cnt, int E) {
  int e = blockIdx.x * 256 + threadIdx.x;
  if (e < E) atomicAdd(&cnt[ei[E + e]], 1);
}

__global__ __launch_bounds__(256) void scan1_kernel(const int* __restrict__ cnt,
                                                    int* off, int* bsum, int N) {
  __shared__ int s[256];
  const int tid = threadIdx.x;
  const int gid = blockIdx.x * 256 + tid;
  const int v = (gid < N) ? cnt[gid] : 0;
  s[tid] = v;
  for (int o = 1; o < 256; o <<= 1) {
    __syncthreads();
    int t = (tid >= o) ? s[tid - o] : 0;
    __syncthreads();
    s[tid] += t;
  }
  if (gid < N) off[gid] = s[tid] - v;
  if (tid == 255) bsum[blockIdx.x] = s[255];
}

__global__ __launch_bounds__(512) void scan2_kernel(int* bsum, int nb) {
  __shared__ int s[512];
  const int tid = threadIdx.x;
  const int v = (tid < nb) ? bsum[tid] : 0;
  s[tid] = v;
  for (int o = 1; o < 512; o <<= 1) {
    __syncthreads();
    int t = (tid >= o) ? s[tid - o] : 0;
    __syncthreads();
    s[tid] += t;
  }
  if (tid < nb) bsum[tid] = s[tid] - v;
}

__global__ __launch_bounds__(256) void scan3_kernel(int* off, int* cur,
                                                    const int* __restrict__ bsum,
                                                    int N) {
  int gid = blockIdx.x * 256 + threadIdx.x;
  if (gid < N) {
    int v = off[gid] + bsum[blockIdx.x];
    off[gid] = v;
    cur[gid] = v;
  }
}

__global__ __launch_bounds__(256) void rank_kernel(const int* __restrict__ ei,
                                                   int* cur, int* rank, int E) {
  int e = blockIdx.x * 256 + threadIdx.x;
  if (e < E) rank[e] = atomicAdd(&cur[ei[E + e]], 1);
}

// ---------- phase 2a: MFMA edge message -> CSR slot (bf16), no LDS ----------
// Cp[out][edge] = W_edge . attr^T ; lane holds 4 consecutive out-chs of 1 edge.
__global__ __launch_bounds__(256) void msg_mfma_kernel(
    const float* __restrict__ x, const int* __restrict__ ei,
    const int* __restrict__ rank, const float* __restrict__ attr,
    const unsigned short* __restrict__ Web,
    unsigned short* __restrict__ msg, int E) {
  const int lane = threadIdx.x & 63;
  const int l15 = lane & 15;
  const int l4 = lane >> 4;
  const int gw = (blockIdx.x * 256 + threadIdx.x) >> 6;
  const int nw = gridDim.x * 4;
  // Preload A-frags: af[m][s] = W_edge rows (bf16), A[row=l15][k=l4*8+j]
  short8 af[8][2];
  #pragma unroll
  for (int m = 0; m < 8; ++m)
    #pragma unroll
    for (int s = 0; s < 2; ++s)
      af[m][s] = *(const short8*)&Web[(m * 16 + l15) * 64 + s * 32 + l4 * 8];
  const int ntiles = (E + 15) >> 4;
  for (int t = gw; t < ntiles; t += nw) {
    const int e0 = t * 16 + l15;
    const int e = (e0 < E) ? e0 : (E - 1);
    const int sidx = ei[e];
    const int p = rank[e];
    f32x4 acc[8];
    #pragma unroll
    for (int m = 0; m < 8; ++m) acc[m] = (f32x4){0.f, 0.f, 0.f, 0.f};
    #pragma unroll
    for (int s = 0; s < 2; ++s) {
      const float4 q0 = *(const float4*)&attr[(size_t)e * 64 + s * 32 + l4 * 8];
      const float4 q1 = *(const float4*)&attr[(size_t)e * 64 + s * 32 + l4 * 8 + 4];
      short8 bt;
      bt[0] = (short)f2bf(q0.x); bt[1] = (short)f2bf(q0.y);
      bt[2] = (short)f2bf(q0.z); bt[3] = (short)f2bf(q0.w);
      bt[4] = (short)f2bf(q1.x); bt[5] = (short)f2bf(q1.y);
      bt[6] = (short)f2bf(q1.z); bt[7] = (short)f2bf(q1.w);
      #pragma unroll
      for (int m = 0; m < 8; ++m)
        acc[m] = __builtin_amdgcn_mfma_f32_16x16x32_bf16(af[m][s], bt, acc[m], 0, 0, 0);
    }
    const bool ok = (e0 < E);
    #pragma unroll
    for (int m = 0; m < 8; ++m) {
      const float4 xv = *(const float4*)&x[(size_t)sidx * 128 + m * 16 + l4 * 4];
      ushort4 pk;
      pk.x = f2bf(fmaxf(xv.x + acc[m][0], 0.f));
      pk.y = f2bf(fmaxf(xv.y + acc[m][1], 0.f));
      pk.z = f2bf(fmaxf(xv.z + acc[m][2], 0.f));
      pk.w = f2bf(fmaxf(xv.w + acc[m][3], 0.f));
      if (ok) *(ushort4*)&msg[(size_t)p * 128 + m * 16 + l4 * 4] = pk;
    }
  }
}

// ---------- phase 2b: seg-sum + MFMA node GEMMs (wave-private LDS) ----------
__global__ __launch_bounds__(256) void node_mfma_kernel(
    const float* __restrict__ x, const unsigned short* __restrict__ Wnb,
    const unsigned short* __restrict__ Wrb, const float* __restrict__ b_nn,
    const int* __restrict__ off, const int* __restrict__ cnt,
    const unsigned short* __restrict__ msg, float* __restrict__ out, int N) {
  __shared__ __align__(16) unsigned int lds[4][2048];  // per wave: U[16][64] + X[16][64] dwords
  const int tid = threadIdx.x;
  const int w = tid >> 6, lane = tid & 63;
  const int l15 = lane & 15, l4 = lane >> 4;
  unsigned int* U = &lds[w][0];
  unsigned int* X = &lds[w][1024];
  const int gw = (blockIdx.x * 256 + tid) >> 6;
  const int nw = gridDim.x * 4;
  const int ntiles = (N + 15) >> 4;
  for (int t = gw; t < ntiles; t += nw) {
    const int nbase = t * 16;
    // phase 1: per-node CSR segment-sum; lane owns channel pair (2*lane, 2*lane+1)
    for (int j = 0; j < 16; ++j) {
      const int n = nbase + j;
      const int pd = j * 64 + (lane ^ ((j & 7) << 2));  // XOR-swizzled dword idx
      if (n >= N) { U[pd] = 0u; X[pd] = 0u; continue; }
      const int o = off[n];
      const int c = cnt[n];
      float s0 = 0.f, s1 = 0.f;
      const unsigned int* mp = (const unsigned int*)(msg + (size_t)o * 128) + lane;
      for (int q = 0; q < c; ++q) {
        const unsigned int mm = mp[(size_t)q * 64];
        s0 += __uint_as_float(mm << 16);
        s1 += __uint_as_float(mm & 0xffff0000u);
      }
      const float2 xv = *(const float2*)&x[(size_t)n * 128 + lane * 2];
      const float u0 = fmaf(1.00001f, xv.x, s0);
      const float u1 = fmaf(1.00001f, xv.y, s1);
      U[pd] = ((unsigned int)f2bf(u1) << 16) | f2bf(u0);
      X[pd] = ((unsigned int)f2bf(xv.y) << 16) | f2bf(xv.x);
    }
    // phase 2: B-frags from wave-private LDS (swizzled b128 reads)
    short8 bu[4], bx[4];
    #pragma unroll
    for (int s = 0; s < 4; ++s) {
      const int pd = l15 * 64 + ((s * 16 + l4 * 4) ^ ((l15 & 7) << 2));
      bu[s] = *(const short8*)&U[pd];
      bx[s] = *(const short8*)&X[pd];
    }
    const int n = nbase + l15;
    #pragma unroll
    for (int m = 0; m < 8; ++m) {
      f32x4 an = (f32x4){0.f, 0.f, 0.f, 0.f};
      f32x4 ar = (f32x4){0.f, 0.f, 0.f, 0.f};
      #pragma unroll
      for (int s = 0; s < 4; ++s) {
        const short8 wn = *(const short8*)&Wnb[(m * 16 + l15) * 128 + s * 32 + l4 * 8];
        const short8 wr = *(const short8*)&Wrb[(m * 16 + l15) * 128 + s * 32 + l4 * 8];
        an = __builtin_amdgcn_mfma_f32_16x16x32_bf16(wn, bu[s], an, 0, 0, 0);
        ar = __builtin_amdgcn_mfma_f32_16x16x32_bf16(wr, bx[s], ar, 0, 0, 0);
      }
      const float4 bb = *(const float4*)&b_nn[m * 16 + l4 * 4];
      float4 o4;
      o4.x = (fmaxf(an[0] + bb.x, 0.f) + ar[0]) * INV_SQRT2;
      o4.y = (fmaxf(an[1] + bb.y, 0.f) + ar[1]) * INV_SQRT2;
      o4.z = (fmaxf(an[2] + bb.z, 0.f) + ar[2]) * INV_SQRT2;
      o4.w = (fmaxf(an[3] + bb.w, 0.f) + ar[3]) * INV_SQRT2;
      if (n < N) *(float4*)&out[(size_t)n * 128 + m * 16 + l4 * 4] = o4;
    }
  }
}

// ---------- legacy fallback (round-1 path, atomics) ----------
__global__ __launch_bounds__(256) void edge_kernel_legacy(
    const float* __restrict__ x, const int* __restrict__ ei,
    const float* __restrict__ edge_attr, const float* __restrict__ W_edge,
    float* aggr, int E) {
  __shared__ float Wl[64 * 128];
  __shared__ float Al[32 * 64];
  const int tid = threadIdx.x;
  for (int idx = tid; idx < 128 * 64; idx += 256) {
    int o = idx >> 6, k = idx & 63;
    Wl[k * 128 + o] = W_edge[idx];
  }
  const int og = tid & 31;
  const int er = tid >> 5;
  const int ntiles = (E + 31) >> 5;
  for (int tile = blockIdx.x; tile < ntiles; tile += gridDim.x) {
    __syncthreads();
    {
      const float* src_ptr = edge_attr + (size_t)tile * 32 * 64;
      const int limit = E * 64 - tile * 32 * 64;
      for (int idx = tid; idx < 2048; idx += 256)
        Al[idx] = (idx < limit) ? src_ptr[idx] : 0.f;
    }
    __syncthreads();
    float acc[4][4] = {};
    #pragma unroll 4
    for (int k = 0; k < 64; ++k) {
      const float4 w = *(const float4*)&Wl[k * 128 + og * 4];
      #pragma unroll
      for (int j = 0; j < 4; ++j) {
        const float a = Al[(er * 4 + j) * 64 + k];
        acc[j][0] = fmaf(a, w.x, acc[j][0]);
        acc[j][1] = fmaf(a, w.y, acc[j][1]);
        acc[j][2] = fmaf(a, w.z, acc[j][2]);
        acc[j][3] = fmaf(a, w.w, acc[j][3]);
      }
    }
    #pragma unroll
    for (int j = 0; j < 4; ++j) {
      const int e = tile * 32 + er * 4 + j;
      if (e < E) {
        const int s = ei[e];
        const int d = ei[E + e];
        const float4 xv = *(const float4*)&x[(size_t)s * 128 + og * 4];
        float* ap = aggr + (size_t)d * 128 + og * 4;
        atomicAdd(ap + 0, fmaxf(xv.x + acc[j][0], 0.f));
        atomicAdd(ap + 1, fmaxf(xv.y + acc[j][1], 0.f));
        atomicAdd(ap + 2, fmaxf(xv.z + acc[j][2], 0.f));
        atomicAdd(ap + 3, fmaxf(xv.w + acc[j][3], 0.f));
      }
    }
  }
}

__global__ __launch_bounds__(256) void node_kernel_legacy(
    const float* __restrict__ x, const float* __restrict__ WT,
    const float* __restrict__ b_nn, float* io, int N) {
  __shared__ float Ul[16 * 128];
  __shared__ float Xl[16 * 128];
  const int tid = threadIdx.x;
  const int og = tid & 31;
  const int nr = tid >> 5;
  const float* WnnT = WT;
  const float* WresT = WT + 128 * 128;
  const int ntiles = (N + 15) >> 4;
  for (int tile = blockIdx.x; tile < ntiles; tile += gridDim.x) {
    __syncthreads();
    {
      const size_t base = (size_t)tile * 16 * 128;
      const int limit = N * 128 - (int)base;
      for (int idx = tid; idx < 2048; idx += 256) {
        const float xv = (idx < limit) ? x[base + idx] : 0.f;
        const float av = (idx < limit) ? io[base + idx] : 0.f;
        Xl[idx] = xv;
        Ul[idx] = fmaf(1.00001f, xv, av);
      }
    }
    __syncthreads();
    float accn[2][4] = {}, accr[2][4] = {};
    #pragma unroll 4
    for (int kk = 0; kk < 128; ++kk) {
      const float4 wn = *(const float4*)&WnnT[kk * 128 + og * 4];
      const float4 wr = *(const float4*)&WresT[kk * 128 + og * 4];
      #pragma unroll
      for (int j = 0; j < 2; ++j) {
        const float u = Ul[(nr * 2 + j) * 128 + kk];
        const float xx = Xl[(nr * 2 + j) * 128 + kk];
        accn[j][0] = fmaf(u, wn.x, accn[j][0]);
        accn[j][1] = fmaf(u, wn.y, accn[j][1]);
        accn[j][2] = fmaf(u, wn.z, accn[j][2]);
        accn[j][3] = fmaf(u, wn.w, accn[j][3]);
        accr[j][0] = fmaf(xx, wr.x, accr[j][0]);
        accr[j][1] = fmaf(xx, wr.y, accr[j][1]);
        accr[j][2] = fmaf(xx, wr.z, accr[j][2]);
        accr[j][3] = fmaf(xx, wr.w, accr[j][3]);
      }
    }
    const float4 b = *(const float4*)&b_nn[og * 4];
    #pragma unroll
    for (int j = 0; j < 2; ++j) {
      const int n = tile * 16 + nr * 2 + j;
      if (n < N) {
        float4 o4;
        o4.x = (fmaxf(accn[j][0] + b.x, 0.f) + accr[j][0]) * INV_SQRT2;
        o4.y = (fmaxf(accn[j][1] + b.y, 0.f) + accr[j][1]) * INV_SQRT2;
        o4.z = (fmaxf(accn[j][2] + b.z, 0.f) + accr[j][2]) * INV_SQRT2;
        o4.w = (fmaxf(accn[j][3] + b.w, 0.f) + accr[j][3]) * INV_SQRT2;
        *(float4*)&io[(size_t)n * 128 + og * 4] = o4;
      }
    }
  }
}

extern "C" void kernel_launch(void* const* d_in, const int* in_sizes, int n_in,
                              void* d_out, int out_size, void* d_ws, size_t ws_size,
                              hipStream_t stream) {
  const float* x      = (const float*)d_in[0];
  const int*   ei     = (const int*)d_in[1];
  const float* ea     = (const float*)d_in[2];
  const float* W_edge = (const float*)d_in[3];
  const float* W_nn   = (const float*)d_in[4];
  const float* b_nn   = (const float*)d_in[5];
  const float* W_res  = (const float*)d_in[6];
  float* out = (float*)d_out;
  const int N = in_sizes[0] / 128;
  const int E = in_sizes[2] / 64;

  char* ws = (char*)d_ws;
  const size_t WT_OFF   = 0;                       // 131072 B (legacy f32 WT)
  const size_t WEB_OFF  = 131072;                  // 16384 B  (W_edge bf16)
  const size_t WNB_OFF  = WEB_OFF + 16384;         // 32768 B  (W_nn bf16)
  const size_t WRB_OFF  = WNB_OFF + 32768;         // 32768 B  (W_res bf16)
  const size_t CNT_OFF  = WRB_OFF + 32768;
  const size_t OFF_OFF  = CNT_OFF + (size_t)N * 4;
  const size_t CUR_OFF  = OFF_OFF + (size_t)N * 4;
  const size_t BSUM_OFF = CUR_OFF + (size_t)N * 4;
  const size_t RANK_OFF = (BSUM_OFF + 2048 + 255) & ~(size_t)255;
  const size_t MSG_OFF  = (RANK_OFF + (size_t)E * 4 + 255) & ~(size_t)255;
  const size_t NEED     = MSG_OFF + (size_t)E * 128 * 2;

  float* WT = (float*)(ws + WT_OFF);
  unsigned short* Web = (unsigned short*)(ws + WEB_OFF);
  unsigned short* Wnb = (unsigned short*)(ws + WNB_OFF);
  unsigned short* Wrb = (unsigned short*)(ws + WRB_OFF);
  prep_kernel<<<64, 256, 0, stream>>>(W_edge, W_nn, W_res, WT, Web, Wnb, Wrb);

  if (ws_size >= NEED) {
    int* cnt  = (int*)(ws + CNT_OFF);
    int* off  = (int*)(ws + OFF_OFF);
    int* cur  = (int*)(ws + CUR_OFF);
    int* bsum = (int*)(ws + BSUM_OFF);
    int* rank = (int*)(ws + RANK_OFF);
    unsigned short* msg = (unsigned short*)(ws + MSG_OFF);

    const int nb = (N + 255) / 256;   // <= 512
    hipMemsetAsync(cnt, 0, (size_t)N * 4, stream);
    hist_kernel<<<(E + 255) / 256, 256, 0, stream>>>(ei, cnt, E);
    scan1_kernel<<<nb, 256, 0, stream>>>(cnt, off, bsum, N);
    scan2_kernel<<<1, 512, 0, stream>>>(bsum, nb);
    scan3_kernel<<<nb, 256, 0, stream>>>(off, cur, bsum, N);
    rank_kernel<<<(E + 255) / 256, 256, 0, stream>>>(ei, cur, rank, E);

    const int etiles = (E + 15) / 16;
    const int eblocks = (etiles + 3) / 4;
    msg_mfma_kernel<<<(eblocks < 2048 ? eblocks : 2048), 256, 0, stream>>>(
        x, ei, rank, ea, Web, msg, E);
    const int ntilesn = (N + 15) / 16;
    const int nblocks = (ntilesn + 3) / 4;
    node_mfma_kernel<<<nblocks, 256, 0, stream>>>(
        x, Wnb, Wrb, b_nn, off, cnt, msg, out, N);
  } else {
    hipMemsetAsync(d_out, 0, (size_t)N * 128 * sizeof(float), stream);
    const int etiles = (E + 31) / 32;
    edge_kernel_legacy<<<(etiles < 4096 ? etiles : 4096), 256, 0, stream>>>(
        x, ei, ea, W_edge, out, E);
    const int ntiles = (N + 15) / 16;
    node_kernel_legacy<<<(ntiles < 2048 ? ntiles : 2048), 256, 0, stream>>>(
        x, WT, b_nn, out, N);
  }
}

// Round 5
// 278.408 us; speedup vs baseline: 1.8281x; 1.8281x over previous
//
#include <hip/hip_runtime.h>
#include <hip/hip_bf16.h>

#define INV_SQRT2 0.7071067811865475f

typedef __attribute__((ext_vector_type(8))) short short8;
typedef __attribute__((ext_vector_type(4))) float f32x4;

static __device__ __forceinline__ unsigned short f2bf(float f) {
  __hip_bfloat16 h = __float2bfloat16(f);
  return *(unsigned short*)&h;
}

// ---------- prep: bf16 weight copies (+ legacy f32 k-major WT) ----------
__global__ __launch_bounds__(256) void prep_kernel(
    const float* __restrict__ W_edge, const float* __restrict__ W_nn,
    const float* __restrict__ W_res, float* __restrict__ WT,
    unsigned short* __restrict__ Web, unsigned short* __restrict__ Wnb,
    unsigned short* __restrict__ Wrb) {
  int idx = blockIdx.x * 256 + threadIdx.x;
  if (idx < 8192) Web[idx] = f2bf(W_edge[idx]);
  if (idx < 16384) {
    Wnb[idx] = f2bf(W_nn[idx]);
    Wrb[idx] = f2bf(W_res[idx]);
    int o = idx >> 7, k = idx & 127;
    WT[k * 128 + o] = W_nn[idx];
    WT[16384 + k * 128 + o] = W_res[idx];
  }
}

// ---------- CSR build ----------
__global__ __launch_bounds__(256) void hist_kernel(const int* __restrict__ ei,
                                                   int* cnt, int E) {
  int e = blockIdx.x * 256 + threadIdx.x;
  if (e < E) atomicAdd(&cnt[ei[E + e]], 1);
}

__global__ __launch_bounds__(256) void scan1_kernel(const int* __restrict__ cnt,
                                                    int* off, int* bsum, int N) {
  __shared__ int s[256];
  const int tid = threadIdx.x;
  const int gid = blockIdx.x * 256 + tid;
  const int v = (gid < N) ? cnt[gid] : 0;
  s[tid] = v;
  for (int o = 1; o < 256; o <<= 1) {
    __syncthreads();
    int t = (tid >= o) ? s[tid - o] : 0;
    __syncthreads();
    s[tid] += t;
  }
  if (gid < N) off[gid] = s[tid] - v;
  if (tid == 255) bsum[blockIdx.x] = s[255];
}

__global__ __launch_bounds__(512) void scan2_kernel(int* bsum, int nb) {
  __shared__ int s[512];
  const int tid = threadIdx.x;
  const int v = (tid < nb) ? bsum[tid] : 0;
  s[tid] = v;
  for (int o = 1; o < 512; o <<= 1) {
    __syncthreads();
    int t = (tid >= o) ? s[tid - o] : 0;
    __syncthreads();
    s[tid] += t;
  }
  if (tid < nb) bsum[tid] = s[tid] - v;
}

__global__ __launch_bounds__(256) void scan3_kernel(int* off, int* cur,
                                                    const int* __restrict__ bsum,
                                                    int N) {
  int gid = blockIdx.x * 256 + threadIdx.x;
  if (gid < N) {
    int v = off[gid] + bsum[blockIdx.x];
    off[gid] = v;
    cur[gid] = v;
  }
}

__global__ __launch_bounds__(256) void rank_kernel(const int* __restrict__ ei,
                                                   int* cur, int* rank, int E) {
  int e = blockIdx.x * 256 + threadIdx.x;
  if (e < E) rank[e] = atomicAdd(&cur[ei[E + e]], 1);
}

// ---------- phase 2a: MFMA edge message -> CSR slot (bf16), no LDS ----------
__global__ __launch_bounds__(256) void msg_mfma_kernel(
    const float* __restrict__ x, const int* __restrict__ ei,
    const int* __restrict__ rank, const float* __restrict__ attr,
    const unsigned short* __restrict__ Web,
    unsigned short* __restrict__ msg, int E) {
  const int lane = threadIdx.x & 63;
  const int l15 = lane & 15;
  const int l4 = lane >> 4;
  const int gw = (blockIdx.x * 256 + threadIdx.x) >> 6;
  const int nw = gridDim.x * 4;
  short8 af[8][2];
  #pragma unroll
  for (int m = 0; m < 8; ++m)
    #pragma unroll
    for (int s = 0; s < 2; ++s)
      af[m][s] = *(const short8*)&Web[(m * 16 + l15) * 64 + s * 32 + l4 * 8];
  const int ntiles = (E + 15) >> 4;
  for (int t = gw; t < ntiles; t += nw) {
    const int e0 = t * 16 + l15;
    const int e = (e0 < E) ? e0 : (E - 1);
    const int sidx = ei[e];
    const int p = rank[e];
    f32x4 acc[8];
    #pragma unroll
    for (int m = 0; m < 8; ++m) acc[m] = (f32x4){0.f, 0.f, 0.f, 0.f};
    #pragma unroll
    for (int s = 0; s < 2; ++s) {
      const float4 q0 = *(const float4*)&attr[(size_t)e * 64 + s * 32 + l4 * 8];
      const float4 q1 = *(const float4*)&attr[(size_t)e * 64 + s * 32 + l4 * 8 + 4];
      short8 bt;
      bt[0] = (short)f2bf(q0.x); bt[1] = (short)f2bf(q0.y);
      bt[2] = (short)f2bf(q0.z); bt[3] = (short)f2bf(q0.w);
      bt[4] = (short)f2bf(q1.x); bt[5] = (short)f2bf(q1.y);
      bt[6] = (short)f2bf(q1.z); bt[7] = (short)f2bf(q1.w);
      #pragma unroll
      for (int m = 0; m < 8; ++m)
        acc[m] = __builtin_amdgcn_mfma_f32_16x16x32_bf16(af[m][s], bt, acc[m], 0, 0, 0);
    }
    const bool ok = (e0 < E);
    #pragma unroll
    for (int m = 0; m < 8; ++m) {
      const float4 xv = *(const float4*)&x[(size_t)sidx * 128 + m * 16 + l4 * 4];
      ushort4 pk;
      pk.x = f2bf(fmaxf(xv.x + acc[m][0], 0.f));
      pk.y = f2bf(fmaxf(xv.y + acc[m][1], 0.f));
      pk.z = f2bf(fmaxf(xv.z + acc[m][2], 0.f));
      pk.w = f2bf(fmaxf(xv.w + acc[m][3], 0.f));
      if (ok) *(ushort4*)&msg[(size_t)p * 128 + m * 16 + l4 * 4] = pk;
    }
  }
}

// ---------- phase 2b-1: TLP segment-sum. thread = (node, dword channel-pair) ----------
// U[n][d] = packed bf16x2 of (1+eps)*x + sum(msg rows)   -- coalesced, no LDS
__global__ __launch_bounds__(256) void aggr_kernel(
    const float* __restrict__ x, const int* __restrict__ off,
    const int* __restrict__ cnt, const unsigned int* __restrict__ msg32,
    unsigned int* __restrict__ U, int N) {
  const int idx = blockIdx.x * 256 + threadIdx.x;
  if (idx >= N * 64) return;
  const int n = idx >> 6, d = idx & 63;
  const int o = off[n], c = cnt[n];
  float a0 = 0.f, a1 = 0.f, b0 = 0.f, b1 = 0.f;
  const unsigned int* p = msg32 + (size_t)o * 64 + d;
  int q = 0;
  for (; q + 4 <= c; q += 4) {
    const unsigned int m0 = p[0], m1 = p[64], m2 = p[128], m3 = p[192];
    a0 += __uint_as_float(m0 << 16) + __uint_as_float(m1 << 16);
    b0 += __uint_as_float(m2 << 16) + __uint_as_float(m3 << 16);
    a1 += __uint_as_float(m0 & 0xffff0000u) + __uint_as_float(m1 & 0xffff0000u);
    b1 += __uint_as_float(m2 & 0xffff0000u) + __uint_as_float(m3 & 0xffff0000u);
    p += 256;
  }
  for (; q < c; ++q) {
    const unsigned int mm = p[0];
    a0 += __uint_as_float(mm << 16);
    a1 += __uint_as_float(mm & 0xffff0000u);
    p += 64;
  }
  const float2 xv = *(const float2*)&x[(size_t)n * 128 + d * 2];
  const float u0 = fmaf(1.00001f, xv.x, a0 + b0);
  const float u1 = fmaf(1.00001f, xv.y, a1 + b1);
  U[(size_t)n * 64 + d] = ((unsigned int)f2bf(u1) << 16) | f2bf(u0);
}

// ---------- phase 2b-2: streaming MFMA node GEMMs, no LDS ----------
__global__ __launch_bounds__(256) void gemm_kernel(
    const float* __restrict__ x, const unsigned short* __restrict__ Ub,
    const unsigned short* __restrict__ Wnb, const unsigned short* __restrict__ Wrb,
    const float* __restrict__ b_nn, float* __restrict__ out, int N) {
  const int lane = threadIdx.x & 63;
  const int l15 = lane & 15, l4 = lane >> 4;
  const int gw = (blockIdx.x * 256 + threadIdx.x) >> 6;
  const int ntiles = (N + 15) >> 4;
  if (gw >= ntiles) return;
  const int n0 = gw * 16 + l15;
  const int n = (n0 < N) ? n0 : (N - 1);
  short8 bu[4], bx[4];
  #pragma unroll
  for (int s = 0; s < 4; ++s) {
    bu[s] = *(const short8*)&Ub[(size_t)n * 128 + s * 32 + l4 * 8];
    const float4 q0 = *(const float4*)&x[(size_t)n * 128 + s * 32 + l4 * 8];
    const float4 q1 = *(const float4*)&x[(size_t)n * 128 + s * 32 + l4 * 8 + 4];
    short8 bt;
    bt[0] = (short)f2bf(q0.x); bt[1] = (short)f2bf(q0.y);
    bt[2] = (short)f2bf(q0.z); bt[3] = (short)f2bf(q0.w);
    bt[4] = (short)f2bf(q1.x); bt[5] = (short)f2bf(q1.y);
    bt[6] = (short)f2bf(q1.z); bt[7] = (short)f2bf(q1.w);
    bx[s] = bt;
  }
  const bool ok = (n0 < N);
  #pragma unroll
  for (int m = 0; m < 8; ++m) {
    f32x4 an = (f32x4){0.f, 0.f, 0.f, 0.f};
    f32x4 ar = (f32x4){0.f, 0.f, 0.f, 0.f};
    #pragma unroll
    for (int s = 0; s < 4; ++s) {
      const short8 wn = *(const short8*)&Wnb[(m * 16 + l15) * 128 + s * 32 + l4 * 8];
      const short8 wr = *(const short8*)&Wrb[(m * 16 + l15) * 128 + s * 32 + l4 * 8];
      an = __builtin_amdgcn_mfma_f32_16x16x32_bf16(wn, bu[s], an, 0, 0, 0);
      ar = __builtin_amdgcn_mfma_f32_16x16x32_bf16(wr, bx[s], ar, 0, 0, 0);
    }
    const float4 bb = *(const float4*)&b_nn[m * 16 + l4 * 4];
    float4 o4;
    o4.x = (fmaxf(an[0] + bb.x, 0.f) + ar[0]) * INV_SQRT2;
    o4.y = (fmaxf(an[1] + bb.y, 0.f) + ar[1]) * INV_SQRT2;
    o4.z = (fmaxf(an[2] + bb.z, 0.f) + ar[2]) * INV_SQRT2;
    o4.w = (fmaxf(an[3] + bb.w, 0.f) + ar[3]) * INV_SQRT2;
    if (ok) *(float4*)&out[(size_t)n0 * 128 + m * 16 + l4 * 4] = o4;
  }
}

// ---------- legacy fallback (round-1 path, atomics) ----------
__global__ __launch_bounds__(256) void edge_kernel_legacy(
    const float* __restrict__ x, const int* __restrict__ ei,
    const float* __restrict__ edge_attr, const float* __restrict__ W_edge,
    float* aggr, int E) {
  __shared__ float Wl[64 * 128];
  __shared__ float Al[32 * 64];
  const int tid = threadIdx.x;
  for (int idx = tid; idx < 128 * 64; idx += 256) {
    int o = idx >> 6, k = idx & 63;
    Wl[k * 128 + o] = W_edge[idx];
  }
  const int og = tid & 31;
  const int er = tid >> 5;
  const int ntiles = (E + 31) >> 5;
  for (int tile = blockIdx.x; tile < ntiles; tile += gridDim.x) {
    __syncthreads();
    {
      const float* src_ptr = edge_attr + (size_t)tile * 32 * 64;
      const int limit = E * 64 - tile * 32 * 64;
      for (int idx = tid; idx < 2048; idx += 256)
        Al[idx] = (idx < limit) ? src_ptr[idx] : 0.f;
    }
    __syncthreads();
    float acc[4][4] = {};
    #pragma unroll 4
    for (int k = 0; k < 64; ++k) {
      const float4 w = *(const float4*)&Wl[k * 128 + og * 4];
      #pragma unroll
      for (int j = 0; j < 4; ++j) {
        const float a = Al[(er * 4 + j) * 64 + k];
        acc[j][0] = fmaf(a, w.x, acc[j][0]);
        acc[j][1] = fmaf(a, w.y, acc[j][1]);
        acc[j][2] = fmaf(a, w.z, acc[j][2]);
        acc[j][3] = fmaf(a, w.w, acc[j][3]);
      }
    }
    #pragma unroll
    for (int j = 0; j < 4; ++j) {
      const int e = tile * 32 + er * 4 + j;
      if (e < E) {
        const int s = ei[e];
        const int d = ei[E + e];
        const float4 xv = *(const float4*)&x[(size_t)s * 128 + og * 4];
        float* ap = aggr + (size_t)d * 128 + og * 4;
        atomicAdd(ap + 0, fmaxf(xv.x + acc[j][0], 0.f));
        atomicAdd(ap + 1, fmaxf(xv.y + acc[j][1], 0.f));
        atomicAdd(ap + 2, fmaxf(xv.z + acc[j][2], 0.f));
        atomicAdd(ap + 3, fmaxf(xv.w + acc[j][3], 0.f));
      }
    }
  }
}

__global__ __launch_bounds__(256) void node_kernel_legacy(
    const float* __restrict__ x, const float* __restrict__ WT,
    const float* __restrict__ b_nn, float* io, int N) {
  __shared__ float Ul[16 * 128];
  __shared__ float Xl[16 * 128];
  const int tid = threadIdx.x;
  const int og = tid & 31;
  const int nr = tid >> 5;
  const float* WnnT = WT;
  const float* WresT = WT + 128 * 128;
  const int ntiles = (N + 15) >> 4;
  for (int tile = blockIdx.x; tile < ntiles; tile += gridDim.x) {
    __syncthreads();
    {
      const size_t base = (size_t)tile * 16 * 128;
      const int limit = N * 128 - (int)base;
      for (int idx = tid; idx < 2048; idx += 256) {
        const float xv = (idx < limit) ? x[base + idx] : 0.f;
        const float av = (idx < limit) ? io[base + idx] : 0.f;
        Xl[idx] = xv;
        Ul[idx] = fmaf(1.00001f, xv, av);
      }
    }
    __syncthreads();
    float accn[2][4] = {}, accr[2][4] = {};
    #pragma unroll 4
    for (int kk = 0; kk < 128; ++kk) {
      const float4 wn = *(const float4*)&WnnT[kk * 128 + og * 4];
      const float4 wr = *(const float4*)&WresT[kk * 128 + og * 4];
      #pragma unroll
      for (int j = 0; j < 2; ++j) {
        const float u = Ul[(nr * 2 + j) * 128 + kk];
        const float xx = Xl[(nr * 2 + j) * 128 + kk];
        accn[j][0] = fmaf(u, wn.x, accn[j][0]);
        accn[j][1] = fmaf(u, wn.y, accn[j][1]);
        accn[j][2] = fmaf(u, wn.z, accn[j][2]);
        accn[j][3] = fmaf(u, wn.w, accn[j][3]);
        accr[j][0] = fmaf(xx, wr.x, accr[j][0]);
        accr[j][1] = fmaf(xx, wr.y, accr[j][1]);
        accr[j][2] = fmaf(xx, wr.z, accr[j][2]);
        accr[j][3] = fmaf(xx, wr.w, accr[j][3]);
      }
    }
    const float4 b = *(const float4*)&b_nn[og * 4];
    #pragma unroll
    for (int j = 0; j < 2; ++j) {
      const int n = tile * 16 + nr * 2 + j;
      if (n < N) {
        float4 o4;
        o4.x = (fmaxf(accn[j][0] + b.x, 0.f) + accr[j][0]) * INV_SQRT2;
        o4.y = (fmaxf(accn[j][1] + b.y, 0.f) + accr[j][1]) * INV_SQRT2;
        o4.z = (fmaxf(accn[j][2] + b.z, 0.f) + accr[j][2]) * INV_SQRT2;
        o4.w = (fmaxf(accn[j][3] + b.w, 0.f) + accr[j][3]) * INV_SQRT2;
        *(float4*)&io[(size_t)n * 128 + og * 4] = o4;
      }
    }
  }
}

extern "C" void kernel_launch(void* const* d_in, const int* in_sizes, int n_in,
                              void* d_out, int out_size, void* d_ws, size_t ws_size,
                              hipStream_t stream) {
  const float* x      = (const float*)d_in[0];
  const int*   ei     = (const int*)d_in[1];
  const float* ea     = (const float*)d_in[2];
  const float* W_edge = (const float*)d_in[3];
  const float* W_nn   = (const float*)d_in[4];
  const float* b_nn   = (const float*)d_in[5];
  const float* W_res  = (const float*)d_in[6];
  float* out = (float*)d_out;
  const int N = in_sizes[0] / 128;
  const int E = in_sizes[2] / 64;

  char* ws = (char*)d_ws;
  const size_t WT_OFF   = 0;                       // 131072 B (legacy f32 WT)
  const size_t WEB_OFF  = 131072;
  const size_t WNB_OFF  = WEB_OFF + 16384;
  const size_t WRB_OFF  = WNB_OFF + 32768;
  const size_t CNT_OFF  = WRB_OFF + 32768;
  const size_t OFF_OFF  = CNT_OFF + (size_t)N * 4;
  const size_t CUR_OFF  = OFF_OFF + (size_t)N * 4;
  const size_t BSUM_OFF = CUR_OFF + (size_t)N * 4;
  const size_t RANK_OFF = (BSUM_OFF + 2048 + 255) & ~(size_t)255;
  const size_t MSG_OFF  = (RANK_OFF + (size_t)E * 4 + 255) & ~(size_t)255;
  const size_t U_OFF    = (MSG_OFF + (size_t)E * 256 + 255) & ~(size_t)255;
  const size_t NEED     = U_OFF + (size_t)N * 256;

  float* WT = (float*)(ws + WT_OFF);
  unsigned short* Web = (unsigned short*)(ws + WEB_OFF);
  unsigned short* Wnb = (unsigned short*)(ws + WNB_OFF);
  unsigned short* Wrb = (unsigned short*)(ws + WRB_OFF);
  prep_kernel<<<64, 256, 0, stream>>>(W_edge, W_nn, W_res, WT, Web, Wnb, Wrb);

  if (ws_size >= NEED) {
    int* cnt  = (int*)(ws + CNT_OFF);
    int* off  = (int*)(ws + OFF_OFF);
    int* cur  = (int*)(ws + CUR_OFF);
    int* bsum = (int*)(ws + BSUM_OFF);
    int* rank = (int*)(ws + RANK_OFF);
    unsigned short* msg = (unsigned short*)(ws + MSG_OFF);
    unsigned int* U = (unsigned int*)(ws + U_OFF);

    const int nb = (N + 255) / 256;   // <= 512
    hipMemsetAsync(cnt, 0, (size_t)N * 4, stream);
    hist_kernel<<<(E + 255) / 256, 256, 0, stream>>>(ei, cnt, E);
    scan1_kernel<<<nb, 256, 0, stream>>>(cnt, off, bsum, N);
    scan2_kernel<<<1, 512, 0, stream>>>(bsum, nb);
    scan3_kernel<<<nb, 256, 0, stream>>>(off, cur, bsum, N);
    rank_kernel<<<(E + 255) / 256, 256, 0, stream>>>(ei, cur, rank, E);

    const int etiles = (E + 15) / 16;
    const int eblocks = (etiles + 3) / 4;
    msg_mfma_kernel<<<(eblocks < 2048 ? eblocks : 2048), 256, 0, stream>>>(
        x, ei, rank, ea, Web, msg, E);

    aggr_kernel<<<(N * 64 + 255) / 256, 256, 0, stream>>>(
        x, off, cnt, (const unsigned int*)msg, U, N);

    const int ntilesn = (N + 15) / 16;
    const int nblocks = (ntilesn + 3) / 4;
    gemm_kernel<<<nblocks, 256, 0, stream>>>(
        x, (const unsigned short*)U, Wnb, Wrb, b_nn, out, N);
  } else {
    hipMemsetAsync(d_out, 0, (size_t)N * 128 * sizeof(float), stream);
    const int etiles = (E + 31) / 32;
    edge_kernel_legacy<<<(etiles < 4096 ? etiles : 4096), 256, 0, stream>>>(
        x, ei, ea, W_edge, out, E);
    const int ntiles = (N + 15) / 16;
    node_kernel_legacy<<<(ntiles < 2048 ? ntiles : 2048), 256, 0, stream>>>(
        x, WT, b_nn, out, N);
  }
}